// Round 17
// baseline (418.950 us; speedup 1.0000x reference)
//
#include <hip/hip_runtime.h>
#include <hip/hip_bf16.h>
#include <math.h>

#define NN 262144
#define CC 512
#define BB 1024
#define EPSF 1e-5f

typedef float f32x4 __attribute__((ext_vector_type(4)));

__device__ __forceinline__ int lower_bound_i(const int* __restrict__ a, int n, int v) {
    int lo = 0, hi = n;
    while (lo < hi) { int mid = (lo + hi) >> 1; if (a[mid] < v) lo = mid + 1; else hi = mid; }
    return lo;
}

__device__ __forceinline__ float sigmoidf(float v) { return 1.0f / (1.0f + __expf(-v)); }

// Fused single-instruction DPP reduction steps (v_add_f32_dpp / v_max_f32_dpp).
// 0xB1 = quad_perm xor1, 0x4E = quad_perm xor2,
// 0x124 = row_ror:4, 0x128 = row_ror:8, 0x141 = row_half_mirror
template<int CTRL>
__device__ __forceinline__ float dppAdd(float v) {
    int t = __builtin_amdgcn_update_dpp(0, __float_as_int(v), CTRL, 0xf, 0xf, true);
    return v + __int_as_float(t);
}
template<int CTRL>
__device__ __forceinline__ float dppMax(float v) {
    int t = __builtin_amdgcn_update_dpp(0, __float_as_int(v), CTRL, 0xf, 0xf, true);
    return fmaxf(v, __int_as_float(t));
}

// ---------------- Kernel A: pass 1 + merged finalize -------------------------
// R13 structure, but ISOLATED register diet: weights in LDS (-36 VGPR),
// no prefetch (R12-proven null, -16 VGPR), __launch_bounds__(256,4) pins
// <=64 VGPR -> 4 waves/SIMD -> 16 waves/CU (2x R13's 8).
__global__ __launch_bounds__(256, 4) void kA(
    const float* __restrict__ x, const int* __restrict__ batch,
    const float* __restrict__ sweight, const float* __restrict__ sbias,
    const float* __restrict__ gn_w, const float* __restrict__ gn_b,
    const float* __restrict__ sp_W1, const float* __restrict__ sp_b1,
    const float* __restrict__ sp_W2, const float* __restrict__ sp_b2,
    const float* __restrict__ init_scale,
    const float* __restrict__ ch_W1, const float* __restrict__ ch_b1,
    const float* __restrict__ ch_W2, const float* __restrict__ ch_b2,
    const float* __restrict__ cweight, const float* __restrict__ cbias,
    const float* __restrict__ gms, const float* __restrict__ gw,
    const float* __restrict__ gb,
    float* __restrict__ coef, float* __restrict__ offs,
    float* __restrict__ spgt)
{
    const int b    = blockIdx.x;
    const int tid  = threadIdx.x;
    const int lane = tid & 63;
    const int w    = tid >> 6;      // 4 waves
    const int g    = lane & 15;
    const int q    = lane >> 4;
    const int h0   = q * 4;
    const int kk   = g & 7;

    __shared__ float red[4][5][256];                        // 20 KB
    __shared__ float gap[512];
    __shared__ float part[4][64];
    __shared__ float hch[64];
    __shared__ float sS1[256], sS2[256], sT1[256], sT2[256];
    // weight tables in LDS; 16/8-row tables padded to stride 20 (16B-aligned)
    __shared__ float gw_l[16 * 20], gb_l[16 * 20];
    __shared__ float w1m_l[8 * 20], w1x_l[8 * 20], w1s_l[8 * 20], w2_l[8 * 20];
    __shared__ float b2_l[16], sw_l[16], sb_l[16];

    if (tid < 256) {
        const int gg = tid >> 4, hh = tid & 15;
        gw_l[gg * 20 + hh] = gn_w[tid];
        gb_l[gg * 20 + hh] = gn_b[tid];
    }
    if (tid < 128) {
        const int k2 = tid >> 4, hh = tid & 15;
        w1m_l[k2 * 20 + hh] = sp_W1[hh * 8 + k2];
        w1x_l[k2 * 20 + hh] = sp_W1[(16 + hh) * 8 + k2];
        w1s_l[k2 * 20 + hh] = sp_W1[(32 + hh) * 8 + k2];
        w2_l [k2 * 20 + hh] = sp_W2[k2 * 16 + hh];
    }
    if (tid < 16) {
        b2_l[tid] = sp_b2[tid];
        sw_l[tid] = sweight[tid];
        sb_l[tid] = sbias[tid];
    }
    __syncthreads();

    const int s = lower_bound_i(batch, NN, b);
    const int e = lower_bound_i(batch, NN, b + 1);
    const int cnt = e - s;
    const float tau = tanhf(init_scale[0]);
    const float b1k = sp_b1[kk];

    const int gofs = g * 20 + h0;
    const int kofs = kk * 20 + h0;

    float sc1[4] = {0.f,0.f,0.f,0.f}, sc2[4] = {0.f,0.f,0.f,0.f};
    float st1[4] = {0.f,0.f,0.f,0.f}, st2[4] = {0.f,0.f,0.f,0.f};
    float mxc[4] = {-INFINITY,-INFINITY,-INFINITY,-INFINITY};

    for (int n0 = s + 2 * w; n0 < e; n0 += 8) {
        const int n1 = (n0 + 1 < e) ? n0 + 1 : e - 1;   // clamped dup on tail
        const bool v1 = (n0 + 1 < e);

        // all 4 loads in flight before compute
        const float* r0 = x + (size_t)n0 * CC + g * 32 + h0;
        const float* r1 = x + (size_t)n1 * CC + g * 32 + h0;
        const float4 c40 = *(const float4*)r0;
        const float4 s40 = *(const float4*)(r0 + 16);
        const float4 c41 = *(const float4*)r1;
        const float4 s41 = *(const float4*)(r1 + 16);

        // c-part stats immediately (frees c40/c41)
        {
            const float c0[4] = {c40.x, c40.y, c40.z, c40.w};
#pragma unroll
            for (int j = 0; j < 4; ++j) {
                sc1[j] += c0[j];
                sc2[j] = fmaf(c0[j], c0[j], sc2[j]);
                mxc[j] = fmaxf(mxc[j], c0[j]);
            }
        }
        if (v1) {
            const float c1[4] = {c41.x, c41.y, c41.z, c41.w};
#pragma unroll
            for (int j = 0; j < 4; ++j) {
                sc1[j] += c1[j];
                sc2[j] = fmaf(c1[j], c1[j], sc2[j]);
                mxc[j] = fmaxf(mxc[j], c1[j]);
            }
        }

        float sa[2][4], spg[2][4];
        sa[0][0] = s40.x; sa[0][1] = s40.y; sa[0][2] = s40.z; sa[0][3] = s40.w;
        sa[1][0] = s41.x; sa[1][1] = s41.y; sa[1][2] = s41.z; sa[1][3] = s41.w;

        float ls[2], lq[2];
#pragma unroll
        for (int rr = 0; rr < 2; ++rr) {
            ls[rr] = sa[rr][0] + sa[rr][1] + sa[rr][2] + sa[rr][3];
            lq[rr] = fmaf(sa[rr][0], sa[rr][0], fmaf(sa[rr][1], sa[rr][1],
                     fmaf(sa[rr][2], sa[rr][2], sa[rr][3] * sa[rr][3])));
        }
#pragma unroll
        for (int rr = 0; rr < 2; ++rr) {
            ls[rr] += __shfl_xor(ls[rr], 16); ls[rr] += __shfl_xor(ls[rr], 32);
            lq[rr] += __shfl_xor(lq[rr], 16); lq[rr] += __shfl_xor(lq[rr], 32);
        }
        {
            const f32x4 gwv = *(const f32x4*)&gw_l[gofs];
            const f32x4 gbv = *(const f32x4*)&gb_l[gofs];
            float xn[2][4];
#pragma unroll
            for (int rr = 0; rr < 2; ++rr) {
                const float mu   = ls[rr] * 0.0625f;
                const float var  = lq[rr] * 0.0625f - mu * mu;
                const float rstd = rsqrtf(var + EPSF);
#pragma unroll
                for (int j = 0; j < 4; ++j)
                    xn[rr][j] = fmaf((sa[rr][j] - mu) * rstd, gwv[j], gbv[j]);
            }

            float sm[2][4], s2c[2][4], mx[2][4];
#pragma unroll
            for (int rr = 0; rr < 2; ++rr) {
#pragma unroll
                for (int j = 0; j < 4; ++j) {
                    float v = xn[rr][j];
                    v = dppAdd<0xB1>(v); v = dppAdd<0x4E>(v);
                    v = dppAdd<0x124>(v); v = dppAdd<0x128>(v);
                    sm[rr][j] = v;
                    float u = xn[rr][j] * xn[rr][j];
                    u = dppAdd<0xB1>(u); u = dppAdd<0x4E>(u);
                    u = dppAdd<0x124>(u); u = dppAdd<0x128>(u);
                    s2c[rr][j] = u;
                    float m = xn[rr][j];
                    m = dppMax<0xB1>(m); m = dppMax<0x4E>(m);
                    m = dppMax<0x124>(m); m = dppMax<0x128>(m);
                    mx[rr][j] = m;
                }
            }

            const f32x4 w1m = *(const f32x4*)&w1m_l[kofs];
            const f32x4 w1x = *(const f32x4*)&w1x_l[kofs];
            const f32x4 w1s = *(const f32x4*)&w1s_l[kofs];
            float p[2] = {0.f, 0.f};
#pragma unroll
            for (int rr = 0; rr < 2; ++rr) {
#pragma unroll
                for (int j = 0; j < 4; ++j) {
                    const float mean = sm[rr][j] * 0.0625f;
                    const float ss   = fmaxf(s2c[rr][j] - 16.0f * mean * mean, 0.0f);
                    const float stdc = sqrtf(ss * (1.0f / 15.0f));
                    p[rr] = fmaf(mean, w1m[j], p[rr]);
                    p[rr] = fmaf(mx[rr][j], w1x[j], p[rr]);
                    p[rr] = fmaf(stdc, w1s[j], p[rr]);
                }
            }
#pragma unroll
            for (int rr = 0; rr < 2; ++rr) {
                p[rr] += __shfl_xor(p[rr], 16); p[rr] += __shfl_xor(p[rr], 32);
            }
            const f32x4 w2r = *(const f32x4*)&w2_l[kofs];
            const f32x4 b2v = *(const f32x4*)&b2_l[h0];
            const f32x4 swv = *(const f32x4*)&sw_l[h0];
            const f32x4 sbv = *(const f32x4*)&sb_l[h0];
#pragma unroll
            for (int rr = 0; rr < 2; ++rr) {
                const float hsk = fmaxf(p[rr] + b1k, 0.0f);
#pragma unroll
                for (int j = 0; j < 4; ++j) {
                    float t = hsk * w2r[j];
                    t = dppAdd<0xB1>(t); t = dppAdd<0x4E>(t); t = dppAdd<0x141>(t);
                    spg[rr][j] = fmaf(sigmoidf(t + b2v[j]), 1.0f + swv[j], sbv[j]) + tau;
                }
            }
        }

#pragma unroll
        for (int j = 0; j < 4; ++j) {
            const float os0 = spg[0][j] * sa[0][j];
            st1[j] += os0;
            st2[j] = fmaf(os0, os0, st2[j]);
        }
        if (g == 0)
            *(float4*)(spgt + (size_t)n0 * 16 + h0) =
                make_float4(spg[0][0], spg[0][1], spg[0][2], spg[0][3]);
        if (v1) {
#pragma unroll
            for (int j = 0; j < 4; ++j) {
                const float os1 = spg[1][j] * sa[1][j];
                st1[j] += os1;
                st2[j] = fmaf(os1, os1, st2[j]);
            }
            if (g == 0)
                *(float4*)(spgt + (size_t)n1 * 16 + h0) =
                    make_float4(spg[1][0], spg[1][1], spg[1][2], spg[1][3]);
        }
    }

    // ---- cross-wave reduction ----
    const int ch = g * 16 + h0;
    *(float4*)&red[w][0][ch] = make_float4(sc1[0], sc1[1], sc1[2], sc1[3]);
    *(float4*)&red[w][1][ch] = make_float4(mxc[0], mxc[1], mxc[2], mxc[3]);
    *(float4*)&red[w][2][ch] = make_float4(sc2[0], sc2[1], sc2[2], sc2[3]);
    *(float4*)&red[w][3][ch] = make_float4(st1[0], st1[1], st1[2], st1[3]);
    *(float4*)&red[w][4][ch] = make_float4(st2[0], st2[1], st2[2], st2[3]);
    __syncthreads();
    const float inv = 1.0f / (float)max(cnt, 1);
    {
        const int c = tid;
        float a0 = red[0][0][c] + red[1][0][c] + red[2][0][c] + red[3][0][c];
        float a1 = fmaxf(fmaxf(red[0][1][c], red[1][1][c]), fmaxf(red[2][1][c], red[3][1][c]));
        float a2 = red[0][2][c] + red[1][2][c] + red[2][2][c] + red[3][2][c];
        float a3 = red[0][3][c] + red[1][3][c] + red[2][3][c] + red[3][3][c];
        float a4 = red[0][4][c] + red[1][4][c] + red[2][4][c] + red[3][4][c];
        sS1[c] = a0; sS2[c] = a2; sT1[c] = a3; sT2[c] = a4;
        gap[c] = a0 * inv;
        gap[256 + c] = (cnt > 0) ? a1 : 0.0f;
    }
    __syncthreads();

    // ---- merged finalize (former kF) ----
    {
        const int t = tid & 63, pp = tid >> 6;
        float acc = 0.f;
        for (int i = pp * 128; i < pp * 128 + 128; ++i)
            acc = fmaf(gap[i], ch_W1[i * 64 + t], acc);
        part[pp][t] = acc;
    }
    __syncthreads();
    if (tid < 64)
        hch[tid] = fmaxf(part[0][tid] + part[1][tid] + part[2][tid] + part[3][tid] + ch_b1[tid], 0.0f);
    __syncthreads();
    {
        const int c = tid, gg = c >> 4, h = c & 15;
        float acc = ch_b2[c];
        for (int k = 0; k < 64; ++k) acc = fmaf(hch[k], ch_W2[k * 256 + c], acc);
        const float chg = fmaf(sigmoidf(acc), 1.0f + cweight[h], cbias[h]);
        const float ct = chg + tau;
        const int colc = gg * 32 + h, cols = colc + 16;
        {
            const float S1 = sS1[c], S2 = sS2[c];
            const float m  = ct * S1 * inv;
            const float e2 = ct * ct * S2 * inv;
            const float smv = gms[colc];
            const float gv = fmaxf(e2 - m * m * smv * (2.0f - smv), 0.0f);
            const float A  = gw[colc] * rsqrtf(gv + EPSF);
            coef[b * 512 + colc] = A * ct;
            offs[b * 512 + colc] = gb[colc] - m * smv * A;
        }
        {
            const float T1 = sT1[c], T2 = sT2[c];
            const float m  = T1 * inv;
            const float e2 = T2 * inv;
            const float smv = gms[cols];
            const float gv = fmaxf(e2 - m * m * smv * (2.0f - smv), 0.0f);
            const float A  = gw[cols] * rsqrtf(gv + EPSF);
            coef[b * 512 + cols] = A;
            offs[b * 512 + cols] = gb[cols] - m * smv * A;
        }
    }
}

// ---------------- Kernel B: streaming final write (R16 verbatim) ------------
__global__ void kB(const float* __restrict__ x, const int* __restrict__ batch,
                   const float* __restrict__ coef, const float* __restrict__ offs,
                   const float* __restrict__ spgt, float* __restrict__ out)
{
    const int bb   = blockIdx.x >> 1;
    const int half = blockIdx.x & 1;
    const int b    = BB - 1 - bb;
    const int tid = threadIdx.x;
    const int lane = tid & 63, w = tid >> 6;
    const int l2 = lane * 2;
    const int p0 = (lane >> 3) & 1;

    const int s0 = lower_bound_i(batch, NN, b);
    const int e0 = lower_bound_i(batch, NN, b + 1);
    const int mid = s0 + ((e0 - s0 + 1) >> 1);
    const int s = half ? mid : s0;
    const int e = half ? e0 : mid;

    const float* cfb = coef + (size_t)b * 512;
    const float* ofb = offs + (size_t)b * 512;
    const float cf0 = cfb[l2],       cf1 = cfb[l2 + 1];
    const float cf2 = cfb[128 + l2], cf3 = cfb[129 + l2];
    const float cf4 = cfb[256 + l2], cf5 = cfb[257 + l2];
    const float cf6 = cfb[384 + l2], cf7 = cfb[385 + l2];
    const float of0 = ofb[l2],       of1 = ofb[l2 + 1];
    const float of2 = ofb[128 + l2], of3 = ofb[129 + l2];
    const float of4 = ofb[256 + l2], of5 = ofb[257 + l2];
    const float of6 = ofb[384 + l2], of7 = ofb[385 + l2];

    for (int n0 = s + 2 * w; n0 < e; n0 += 8) {
        const int n1 = (n0 + 1 < e) ? n0 + 1 : e - 1;
        const bool v1 = (n0 + 1 < e);

        const float2* r0 = (const float2*)(x + (size_t)n0 * CC);
        const float2* r1 = (const float2*)(x + (size_t)n1 * CC);
        const float2 xa[2] = { r0[lane],        r1[lane] };
        const float2 xb[2] = { r0[64 + lane],   r1[64 + lane] };
        const float2 xc[2] = { r0[128 + lane],  r1[128 + lane] };
        const float2 xd[2] = { r0[192 + lane],  r1[192 + lane] };
        const float2 sp[2] = {
            *(const float2*)(spgt + (size_t)n0 * 16 + (l2 & 15)),
            *(const float2*)(spgt + (size_t)n1 * 16 + (l2 & 15)) };

#pragma unroll
        for (int rr = 0; rr < 2; ++rr) {
            if (rr == 1 && !v1) break;
            const float me = p0 ? sp[rr].x : 1.0f;
            const float mo = p0 ? sp[rr].y : 1.0f;

            const float v0 = fmaf(cf0 * me, xa[rr].x, of0);
            const float v1f = fmaf(cf1 * mo, xa[rr].y, of1);
            const float v2 = fmaf(cf2 * me, xb[rr].x, of2);
            const float v3 = fmaf(cf3 * mo, xb[rr].y, of3);
            const float v4 = fmaf(cf4 * me, xc[rr].x, of4);
            const float v5 = fmaf(cf5 * mo, xc[rr].y, of5);
            const float v6 = fmaf(cf6 * me, xd[rr].x, of6);
            const float v7 = fmaf(cf7 * mo, xd[rr].y, of7);

            f32x4* o4 = (f32x4*)(out + (size_t)(rr ? n1 : n0) * CC);
            f32x4 pa = {v0, v4, v1f, v5};
            f32x4 pb = {v2, v6, v3, v7};
            o4[lane]      = pa;
            o4[64 + lane] = pb;
        }
    }
}

extern "C" void kernel_launch(void* const* d_in, const int* in_sizes, int n_in,
                              void* d_out, int out_size, void* d_ws, size_t ws_size,
                              hipStream_t stream) {
    (void)in_sizes; (void)n_in; (void)out_size; (void)ws_size;
    const float* x        = (const float*)d_in[0];
    const int*   batch    = (const int*)d_in[1];
    const float* cweight  = (const float*)d_in[3];
    const float* cbias    = (const float*)d_in[4];
    const float* sweight  = (const float*)d_in[5];
    const float* sbias    = (const float*)d_in[6];
    const float* ch_W1    = (const float*)d_in[7];
    const float* ch_b1    = (const float*)d_in[8];
    const float* ch_W2    = (const float*)d_in[9];
    const float* ch_b2    = (const float*)d_in[10];
    const float* gn_w     = (const float*)d_in[11];
    const float* gn_b     = (const float*)d_in[12];
    const float* sp_W1    = (const float*)d_in[13];
    const float* sp_b1    = (const float*)d_in[14];
    const float* sp_W2    = (const float*)d_in[15];
    const float* sp_b2    = (const float*)d_in[16];
    const float* init_sc  = (const float*)d_in[17];
    const float* gnw      = (const float*)d_in[18];
    const float* gnb      = (const float*)d_in[19];
    const float* gms      = (const float*)d_in[20];

    float* ws    = (float*)d_ws;
    float* coef  = ws;                 // BB*512
    float* offs  = coef + BB * 512;    // BB*512
    float* spgt  = offs + BB * 512;    // NN*16
    float* outp  = (float*)d_out;

    kA<<<BB, 256, 0, stream>>>(x, batch, sweight, sbias, gn_w, gn_b,
                               sp_W1, sp_b1, sp_W2, sp_b2, init_sc,
                               ch_W1, ch_b1, ch_W2, ch_b2, cweight, cbias,
                               gms, gnw, gnb, coef, offs, spgt);
    kB<<<BB * 2, 256, 0, stream>>>(x, batch, coef, offs, spgt, outp);
}

// Round 18
// 407.094 us; speedup vs baseline: 1.0291x; 1.0291x over previous
//
#include <hip/hip_runtime.h>
#include <hip/hip_bf16.h>
#include <math.h>

#define NN 262144
#define CC 512
#define BB 1024
#define EPSF 1e-5f

typedef float f32x4 __attribute__((ext_vector_type(4)));

__device__ __forceinline__ int lower_bound_i(const int* __restrict__ a, int n, int v) {
    int lo = 0, hi = n;
    while (lo < hi) { int mid = (lo + hi) >> 1; if (a[mid] < v) lo = mid + 1; else hi = mid; }
    return lo;
}

__device__ __forceinline__ float sigmoidf(float v) { return 1.0f / (1.0f + __expf(-v)); }

// Fused single-instruction DPP reduction steps (v_add_f32_dpp / v_max_f32_dpp).
// 0xB1 = quad_perm xor1, 0x4E = quad_perm xor2,
// 0x124 = row_ror:4, 0x128 = row_ror:8, 0x141 = row_half_mirror
template<int CTRL>
__device__ __forceinline__ float dppAdd(float v) {
    int t = __builtin_amdgcn_update_dpp(0, __float_as_int(v), CTRL, 0xf, 0xf, true);
    return v + __int_as_float(t);
}
template<int CTRL>
__device__ __forceinline__ float dppMax(float v) {
    int t = __builtin_amdgcn_update_dpp(0, __float_as_int(v), CTRL, 0xf, 0xf, true);
    return fmaxf(v, __int_as_float(t));
}

// ---------------- Kernel A: pass 1 + merged finalize (best config: R13) ------
// 2-row ILP + 1-iter prefetch, register weights, inline channel-MLP epilogue.
// Session ledger: kA occupancy levers all measured <=0 (prefetch-null R12,
// 128-VGPR pin -12 R15, LDS-weights+64-pin -12 R17). kA sits at its per-row
// VALU/DPP-chain floor ~= its BW floor; leave as-is.
__global__ void kA(const float* __restrict__ x, const int* __restrict__ batch,
                   const float* __restrict__ sweight, const float* __restrict__ sbias,
                   const float* __restrict__ gn_w, const float* __restrict__ gn_b,
                   const float* __restrict__ sp_W1, const float* __restrict__ sp_b1,
                   const float* __restrict__ sp_W2, const float* __restrict__ sp_b2,
                   const float* __restrict__ init_scale,
                   const float* __restrict__ ch_W1, const float* __restrict__ ch_b1,
                   const float* __restrict__ ch_W2, const float* __restrict__ ch_b2,
                   const float* __restrict__ cweight, const float* __restrict__ cbias,
                   const float* __restrict__ gms, const float* __restrict__ gw,
                   const float* __restrict__ gb,
                   float* __restrict__ coef, float* __restrict__ offs,
                   float* __restrict__ spgt)
{
    const int b    = blockIdx.x;
    const int tid  = threadIdx.x;
    const int lane = tid & 63;
    const int w    = tid >> 6;      // 4 waves
    const int g    = lane & 15;
    const int q    = lane >> 4;
    const int h0   = q * 4;
    const int kk   = g & 7;

    __shared__ float red[4][5][256];                        // 20 KB
    __shared__ float gap[512];
    __shared__ float part[4][64];
    __shared__ float hch[64];
    __shared__ float sS1[256], sS2[256], sT1[256], sT2[256];

    const int s = lower_bound_i(batch, NN, b);
    const int e = lower_bound_i(batch, NN, b + 1);
    const int cnt = e - s;
    const float tau = tanhf(init_scale[0]);

    float gwv[4], gbv[4], b2v[4], swv[4], sbv[4], w1m[4], w1x[4], w1s[4], w2r[4];
#pragma unroll
    for (int j = 0; j < 4; ++j) {
        const int h = h0 + j;
        gwv[j] = gn_w[g * 16 + h];
        gbv[j] = gn_b[g * 16 + h];
        b2v[j] = sp_b2[h];
        swv[j] = sweight[h];
        sbv[j] = sbias[h];
        w1m[j] = sp_W1[h * 8 + kk];
        w1x[j] = sp_W1[(16 + h) * 8 + kk];
        w1s[j] = sp_W1[(32 + h) * 8 + kk];
        w2r[j] = sp_W2[kk * 16 + h];
    }
    const float b1k = sp_b1[kk];

    float sc1[4] = {0.f,0.f,0.f,0.f}, sc2[4] = {0.f,0.f,0.f,0.f};
    float st1[4] = {0.f,0.f,0.f,0.f}, st2[4] = {0.f,0.f,0.f,0.f};
    float mxc[4] = {-INFINITY,-INFINITY,-INFINITY,-INFINITY};

    int n0 = s + 2 * w;
    int n1 = 0; bool v1 = false;
    float4 c40, s40, c41, s41;
    if (n0 < e) {
        n1 = (n0 + 1 < e) ? n0 + 1 : e - 1;
        v1 = (n0 + 1 < e);
        const float* r0 = x + (size_t)n0 * CC + g * 32 + h0;
        const float* r1 = x + (size_t)n1 * CC + g * 32 + h0;
        c40 = *(const float4*)r0;  s40 = *(const float4*)(r0 + 16);
        c41 = *(const float4*)r1;  s41 = *(const float4*)(r1 + 16);
    }

    while (n0 < e) {
        const int m0 = n0 + 8;
        int m1 = 0; bool mv1 = false;
        float4 nc0, ns0, nc1, ns1;
        if (m0 < e) {
            m1 = (m0 + 1 < e) ? m0 + 1 : e - 1;
            mv1 = (m0 + 1 < e);
            const float* r0 = x + (size_t)m0 * CC + g * 32 + h0;
            const float* r1 = x + (size_t)m1 * CC + g * 32 + h0;
            nc0 = *(const float4*)r0;  ns0 = *(const float4*)(r0 + 16);
            nc1 = *(const float4*)r1;  ns1 = *(const float4*)(r1 + 16);
        }

        {
            const float c0[4] = {c40.x, c40.y, c40.z, c40.w};
#pragma unroll
            for (int j = 0; j < 4; ++j) {
                sc1[j] += c0[j];
                sc2[j] = fmaf(c0[j], c0[j], sc2[j]);
                mxc[j] = fmaxf(mxc[j], c0[j]);
            }
        }
        if (v1) {
            const float c1[4] = {c41.x, c41.y, c41.z, c41.w};
#pragma unroll
            for (int j = 0; j < 4; ++j) {
                sc1[j] += c1[j];
                sc2[j] = fmaf(c1[j], c1[j], sc2[j]);
                mxc[j] = fmaxf(mxc[j], c1[j]);
            }
        }

        float sa[2][4], spg[2][4];
        sa[0][0] = s40.x; sa[0][1] = s40.y; sa[0][2] = s40.z; sa[0][3] = s40.w;
        sa[1][0] = s41.x; sa[1][1] = s41.y; sa[1][2] = s41.z; sa[1][3] = s41.w;

        float ls[2], lq[2];
#pragma unroll
        for (int rr = 0; rr < 2; ++rr) {
            ls[rr] = sa[rr][0] + sa[rr][1] + sa[rr][2] + sa[rr][3];
            lq[rr] = fmaf(sa[rr][0], sa[rr][0], fmaf(sa[rr][1], sa[rr][1],
                     fmaf(sa[rr][2], sa[rr][2], sa[rr][3] * sa[rr][3])));
        }
#pragma unroll
        for (int rr = 0; rr < 2; ++rr) {
            ls[rr] += __shfl_xor(ls[rr], 16); ls[rr] += __shfl_xor(ls[rr], 32);
            lq[rr] += __shfl_xor(lq[rr], 16); lq[rr] += __shfl_xor(lq[rr], 32);
        }
        float xn[2][4];
#pragma unroll
        for (int rr = 0; rr < 2; ++rr) {
            const float mu   = ls[rr] * 0.0625f;
            const float var  = lq[rr] * 0.0625f - mu * mu;
            const float rstd = rsqrtf(var + EPSF);
#pragma unroll
            for (int j = 0; j < 4; ++j)
                xn[rr][j] = fmaf((sa[rr][j] - mu) * rstd, gwv[j], gbv[j]);
        }

        float sm[2][4], s2c[2][4], mx[2][4];
#pragma unroll
        for (int rr = 0; rr < 2; ++rr) {
#pragma unroll
            for (int j = 0; j < 4; ++j) {
                float v = xn[rr][j];
                v = dppAdd<0xB1>(v); v = dppAdd<0x4E>(v);
                v = dppAdd<0x124>(v); v = dppAdd<0x128>(v);
                sm[rr][j] = v;
                float u = xn[rr][j] * xn[rr][j];
                u = dppAdd<0xB1>(u); u = dppAdd<0x4E>(u);
                u = dppAdd<0x124>(u); u = dppAdd<0x128>(u);
                s2c[rr][j] = u;
                float m = xn[rr][j];
                m = dppMax<0xB1>(m); m = dppMax<0x4E>(m);
                m = dppMax<0x124>(m); m = dppMax<0x128>(m);
                mx[rr][j] = m;
            }
        }

        float p[2] = {0.f, 0.f};
#pragma unroll
        for (int rr = 0; rr < 2; ++rr) {
#pragma unroll
            for (int j = 0; j < 4; ++j) {
                const float mean = sm[rr][j] * 0.0625f;
                const float ss   = fmaxf(s2c[rr][j] - 16.0f * mean * mean, 0.0f);
                const float stdc = sqrtf(ss * (1.0f / 15.0f));
                p[rr] = fmaf(mean, w1m[j], p[rr]);
                p[rr] = fmaf(mx[rr][j], w1x[j], p[rr]);
                p[rr] = fmaf(stdc, w1s[j], p[rr]);
            }
        }
#pragma unroll
        for (int rr = 0; rr < 2; ++rr) {
            p[rr] += __shfl_xor(p[rr], 16); p[rr] += __shfl_xor(p[rr], 32);
        }
#pragma unroll
        for (int rr = 0; rr < 2; ++rr) {
            const float hsk = fmaxf(p[rr] + b1k, 0.0f);
#pragma unroll
            for (int j = 0; j < 4; ++j) {
                float t = hsk * w2r[j];
                t = dppAdd<0xB1>(t); t = dppAdd<0x4E>(t); t = dppAdd<0x141>(t);
                spg[rr][j] = fmaf(sigmoidf(t + b2v[j]), 1.0f + swv[j], sbv[j]) + tau;
            }
        }

#pragma unroll
        for (int j = 0; j < 4; ++j) {
            const float os0 = spg[0][j] * sa[0][j];
            st1[j] += os0;
            st2[j] = fmaf(os0, os0, st2[j]);
        }
        if (g == 0)
            *(float4*)(spgt + (size_t)n0 * 16 + h0) =
                make_float4(spg[0][0], spg[0][1], spg[0][2], spg[0][3]);
        if (v1) {
#pragma unroll
            for (int j = 0; j < 4; ++j) {
                const float os1 = spg[1][j] * sa[1][j];
                st1[j] += os1;
                st2[j] = fmaf(os1, os1, st2[j]);
            }
            if (g == 0)
                *(float4*)(spgt + (size_t)n1 * 16 + h0) =
                    make_float4(spg[1][0], spg[1][1], spg[1][2], spg[1][3]);
        }

        n0 = m0; n1 = m1; v1 = mv1;
        c40 = nc0; s40 = ns0; c41 = nc1; s41 = ns1;
    }

    // ---- cross-wave reduction ----
    const int ch = g * 16 + h0;
    *(float4*)&red[w][0][ch] = make_float4(sc1[0], sc1[1], sc1[2], sc1[3]);
    *(float4*)&red[w][1][ch] = make_float4(mxc[0], mxc[1], mxc[2], mxc[3]);
    *(float4*)&red[w][2][ch] = make_float4(sc2[0], sc2[1], sc2[2], sc2[3]);
    *(float4*)&red[w][3][ch] = make_float4(st1[0], st1[1], st1[2], st1[3]);
    *(float4*)&red[w][4][ch] = make_float4(st2[0], st2[1], st2[2], st2[3]);
    __syncthreads();
    const float inv = 1.0f / (float)max(cnt, 1);
    {
        const int c = tid;
        float a0 = red[0][0][c] + red[1][0][c] + red[2][0][c] + red[3][0][c];
        float a1 = fmaxf(fmaxf(red[0][1][c], red[1][1][c]), fmaxf(red[2][1][c], red[3][1][c]));
        float a2 = red[0][2][c] + red[1][2][c] + red[2][2][c] + red[3][2][c];
        float a3 = red[0][3][c] + red[1][3][c] + red[2][3][c] + red[3][3][c];
        float a4 = red[0][4][c] + red[1][4][c] + red[2][4][c] + red[3][4][c];
        sS1[c] = a0; sS2[c] = a2; sT1[c] = a3; sT2[c] = a4;
        gap[c] = a0 * inv;
        gap[256 + c] = (cnt > 0) ? a1 : 0.0f;
    }
    __syncthreads();

    // ---- merged finalize (former kF) ----
    {
        const int t = tid & 63, pp = tid >> 6;
        float acc = 0.f;
        for (int i = pp * 128; i < pp * 128 + 128; ++i)
            acc = fmaf(gap[i], ch_W1[i * 64 + t], acc);
        part[pp][t] = acc;
    }
    __syncthreads();
    if (tid < 64)
        hch[tid] = fmaxf(part[0][tid] + part[1][tid] + part[2][tid] + part[3][tid] + ch_b1[tid], 0.0f);
    __syncthreads();
    {
        const int c = tid, gg = c >> 4, h = c & 15;
        float acc = ch_b2[c];
        for (int k = 0; k < 64; ++k) acc = fmaf(hch[k], ch_W2[k * 256 + c], acc);
        const float chg = fmaf(sigmoidf(acc), 1.0f + cweight[h], cbias[h]);
        const float ct = chg + tau;
        const int colc = gg * 32 + h, cols = colc + 16;
        {
            const float S1 = sS1[c], S2 = sS2[c];
            const float m  = ct * S1 * inv;
            const float e2 = ct * ct * S2 * inv;
            const float smv = gms[colc];
            const float gv = fmaxf(e2 - m * m * smv * (2.0f - smv), 0.0f);
            const float A  = gw[colc] * rsqrtf(gv + EPSF);
            coef[b * 512 + colc] = A * ct;
            offs[b * 512 + colc] = gb[colc] - m * smv * A;
        }
        {
            const float T1 = sT1[c], T2 = sT2[c];
            const float m  = T1 * inv;
            const float e2 = T2 * inv;
            const float smv = gms[cols];
            const float gv = fmaxf(e2 - m * m * smv * (2.0f - smv), 0.0f);
            const float A  = gw[cols] * rsqrtf(gv + EPSF);
            coef[b * 512 + cols] = A;
            offs[b * 512 + cols] = gb[cols] - m * smv * A;
        }
    }
}

// ---------------- Kernel B: streaming final write, 2 blocks/segment ---------
// Grid 2048, reverse segment order (L3 reuse of kA's tail), plain stores
// (NT measured neutral R16). Mixed-stream HBM-bound.
__global__ void kB(const float* __restrict__ x, const int* __restrict__ batch,
                   const float* __restrict__ coef, const float* __restrict__ offs,
                   const float* __restrict__ spgt, float* __restrict__ out)
{
    const int bb   = blockIdx.x >> 1;
    const int half = blockIdx.x & 1;
    const int b    = BB - 1 - bb;
    const int tid = threadIdx.x;
    const int lane = tid & 63, w = tid >> 6;
    const int l2 = lane * 2;
    const int p0 = (lane >> 3) & 1;

    const int s0 = lower_bound_i(batch, NN, b);
    const int e0 = lower_bound_i(batch, NN, b + 1);
    const int mid = s0 + ((e0 - s0 + 1) >> 1);
    const int s = half ? mid : s0;
    const int e = half ? e0 : mid;

    const float* cfb = coef + (size_t)b * 512;
    const float* ofb = offs + (size_t)b * 512;
    const float cf0 = cfb[l2],       cf1 = cfb[l2 + 1];
    const float cf2 = cfb[128 + l2], cf3 = cfb[129 + l2];
    const float cf4 = cfb[256 + l2], cf5 = cfb[257 + l2];
    const float cf6 = cfb[384 + l2], cf7 = cfb[385 + l2];
    const float of0 = ofb[l2],       of1 = ofb[l2 + 1];
    const float of2 = ofb[128 + l2], of3 = ofb[129 + l2];
    const float of4 = ofb[256 + l2], of5 = ofb[257 + l2];
    const float of6 = ofb[384 + l2], of7 = ofb[385 + l2];

    for (int n0 = s + 2 * w; n0 < e; n0 += 8) {
        const int n1 = (n0 + 1 < e) ? n0 + 1 : e - 1;
        const bool v1 = (n0 + 1 < e);

        const float2* r0 = (const float2*)(x + (size_t)n0 * CC);
        const float2* r1 = (const float2*)(x + (size_t)n1 * CC);
        const float2 xa[2] = { r0[lane],        r1[lane] };
        const float2 xb[2] = { r0[64 + lane],   r1[64 + lane] };
        const float2 xc[2] = { r0[128 + lane],  r1[128 + lane] };
        const float2 xd[2] = { r0[192 + lane],  r1[192 + lane] };
        const float2 sp[2] = {
            *(const float2*)(spgt + (size_t)n0 * 16 + (l2 & 15)),
            *(const float2*)(spgt + (size_t)n1 * 16 + (l2 & 15)) };

#pragma unroll
        for (int rr = 0; rr < 2; ++rr) {
            if (rr == 1 && !v1) break;
            const float me = p0 ? sp[rr].x : 1.0f;
            const float mo = p0 ? sp[rr].y : 1.0f;

            const float v0 = fmaf(cf0 * me, xa[rr].x, of0);
            const float v1f = fmaf(cf1 * mo, xa[rr].y, of1);
            const float v2 = fmaf(cf2 * me, xb[rr].x, of2);
            const float v3 = fmaf(cf3 * mo, xb[rr].y, of3);
            const float v4 = fmaf(cf4 * me, xc[rr].x, of4);
            const float v5 = fmaf(cf5 * mo, xc[rr].y, of5);
            const float v6 = fmaf(cf6 * me, xd[rr].x, of6);
            const float v7 = fmaf(cf7 * mo, xd[rr].y, of7);

            f32x4* o4 = (f32x4*)(out + (size_t)(rr ? n1 : n0) * CC);
            f32x4 pa = {v0, v4, v1f, v5};
            f32x4 pb = {v2, v6, v3, v7};
            o4[lane]      = pa;
            o4[64 + lane] = pb;
        }
    }
}

extern "C" void kernel_launch(void* const* d_in, const int* in_sizes, int n_in,
                              void* d_out, int out_size, void* d_ws, size_t ws_size,
                              hipStream_t stream) {
    (void)in_sizes; (void)n_in; (void)out_size; (void)ws_size;
    const float* x        = (const float*)d_in[0];
    const int*   batch    = (const int*)d_in[1];
    const float* cweight  = (const float*)d_in[3];
    const float* cbias    = (const float*)d_in[4];
    const float* sweight  = (const float*)d_in[5];
    const float* sbias    = (const float*)d_in[6];
    const float* ch_W1    = (const float*)d_in[7];
    const float* ch_b1    = (const float*)d_in[8];
    const float* ch_W2    = (const float*)d_in[9];
    const float* ch_b2    = (const float*)d_in[10];
    const float* gn_w     = (const float*)d_in[11];
    const float* gn_b     = (const float*)d_in[12];
    const float* sp_W1    = (const float*)d_in[13];
    const float* sp_b1    = (const float*)d_in[14];
    const float* sp_W2    = (const float*)d_in[15];
    const float* sp_b2    = (const float*)d_in[16];
    const float* init_sc  = (const float*)d_in[17];
    const float* gnw      = (const float*)d_in[18];
    const float* gnb      = (const float*)d_in[19];
    const float* gms      = (const float*)d_in[20];

    float* ws    = (float*)d_ws;
    float* coef  = ws;                 // BB*512
    float* offs  = coef + BB * 512;    // BB*512
    float* spgt  = offs + BB * 512;    // NN*16
    float* outp  = (float*)d_out;

    kA<<<BB, 256, 0, stream>>>(x, batch, sweight, sbias, gn_w, gn_b,
                               sp_W1, sp_b1, sp_W2, sp_b2, init_sc,
                               ch_W1, ch_b1, ch_W2, ch_b2, cweight, cbias,
                               gms, gnw, gnb, coef, offs, spgt);
    kB<<<BB * 2, 256, 0, stream>>>(x, batch, coef, offs, spgt, outp);
}